// Round 3
// baseline (412.836 us; speedup 1.0000x reference)
//
#include <hip/hip_runtime.h>
#include <math.h>

#define T 2048
#define HIDDEN 2048
#define NH 16
#define NKV 4
#define HD 128
#define QKV_N 3072   // (16 + 2*4) * 128
#define Q_SIZE 2048  // 16*128
#define KV_SIZE 512  // 4*128

typedef __attribute__((ext_vector_type(8))) short short8;
typedef __attribute__((ext_vector_type(4))) float floatx4;

__device__ __forceinline__ unsigned short f2bf(float f) {
    union { float f; unsigned int u; } v; v.f = f;
    unsigned int u = v.u;
    u += 0x7fffu + ((u >> 16) & 1u);   // round-to-nearest-even
    return (unsigned short)(u >> 16);
}
__device__ __forceinline__ float bf2f(unsigned short h) {
    union { unsigned int u; float f; } v; v.u = ((unsigned int)h) << 16;
    return v.f;
}

// ---------------- cos/sin tables (mrope sectioning) ----------------
__global__ void prep_cossin(const int* __restrict__ positions,
                            float* __restrict__ cosT, float* __restrict__ sinT) {
    int t = blockIdx.x;
    int j = threadIdx.x;           // 0..63
    int row = (j >= 44) ? 0 : ((j & 1) ? 2 : 1);
    int pos = positions[row * T + t];
    double invf = pow(500000.0, -(double)j / 64.0);
    double ang = (double)pos * invf;
    cosT[t * 64 + j] = (float)cos(ang);
    sinT[t * 64 + j] = (float)sin(ang);
}

// ---------------- fp32 -> bf16 convert ----------------
__global__ __launch_bounds__(256) void convert_f32_bf16(const float* __restrict__ in,
                                                        unsigned short* __restrict__ out, int n) {
    int i = (blockIdx.x * 256 + threadIdx.x) * 4;
    if (i + 3 < n) {
        float4 v = *(const float4*)(in + i);
        out[i]     = f2bf(v.x);
        out[i + 1] = f2bf(v.y);
        out[i + 2] = f2bf(v.z);
        out[i + 3] = f2bf(v.w);
    }
}

// ---------------- transpose fp32 -> bf16 : out[c][r] = in[r][c] ----------------
__global__ __launch_bounds__(256) void transpose_f32_bf16(const float* __restrict__ in,
                                                          unsigned short* __restrict__ out,
                                                          int R, int C) {
    __shared__ float tile[32][33];
    int tx = threadIdx.x, ty = threadIdx.y;          // (32,8)
    int c0 = blockIdx.x * 32, r0 = blockIdx.y * 32;
#pragma unroll
    for (int i = 0; i < 4; ++i)
        tile[ty + i * 8][tx] = in[(long)(r0 + ty + i * 8) * C + c0 + tx];
    __syncthreads();
#pragma unroll
    for (int i = 0; i < 4; ++i)
        out[(long)(c0 + ty + i * 8) * R + r0 + tx] = f2bf(tile[tx][ty + i * 8]);
}

// ---------------- transpose bf16 (batched over z) ----------------
__global__ __launch_bounds__(256) void transpose_bf16(const unsigned short* __restrict__ in,
                                                      unsigned short* __restrict__ out,
                                                      int R, int C) {
    __shared__ unsigned short tile[32][33];
    long zo = (long)blockIdx.z * R * C;
    in += zo; out += zo;
    int tx = threadIdx.x, ty = threadIdx.y;
    int c0 = blockIdx.x * 32, r0 = blockIdx.y * 32;
#pragma unroll
    for (int i = 0; i < 4; ++i)
        tile[ty + i * 8][tx] = in[(long)(r0 + ty + i * 8) * C + c0 + tx];
    __syncthreads();
#pragma unroll
    for (int i = 0; i < 4; ++i)
        out[(long)(c0 + ty + i * 8) * R + r0 + tx] = tile[tx][ty + i * 8];
}

// ---------------- rope + split qkv -> q_bf, k_bf, v_bf ----------------
__global__ __launch_bounds__(256) void rope_split(const float* __restrict__ qkv,
                                                  const float* __restrict__ cosT,
                                                  const float* __restrict__ sinT,
                                                  unsigned short* __restrict__ qb,
                                                  unsigned short* __restrict__ kb,
                                                  unsigned short* __restrict__ vb) {
    int t = blockIdx.x, tid = threadIdx.x;
    const float* row = qkv + (long)t * QKV_N;
    const float* ct = cosT + t * 64;
    const float* st = sinT + t * 64;
    for (int i = tid; i < NH * 64; i += 256) {
        int h = i >> 6, j = i & 63;
        float c = ct[j], s = st[j];
        float x1 = row[h * HD + 2 * j], x2 = row[h * HD + 2 * j + 1];
        qb[(long)t * Q_SIZE + h * HD + 2 * j]     = f2bf(x1 * c - x2 * s);
        qb[(long)t * Q_SIZE + h * HD + 2 * j + 1] = f2bf(x2 * c + x1 * s);
    }
    {
        int i = tid;
        int g = i >> 6, j = i & 63;
        float c = ct[j], s = st[j];
        float x1 = row[Q_SIZE + g * HD + 2 * j], x2 = row[Q_SIZE + g * HD + 2 * j + 1];
        kb[(long)t * KV_SIZE + g * HD + 2 * j]     = f2bf(x1 * c - x2 * s);
        kb[(long)t * KV_SIZE + g * HD + 2 * j + 1] = f2bf(x2 * c + x1 * s);
    }
    for (int i = tid; i < KV_SIZE; i += 256) {
        int g = i >> 7, d = i & 127;
        vb[((long)g * T + t) * HD + d] = f2bf(row[Q_SIZE + KV_SIZE + g * HD + d]);
    }
}

// ---------------- GEMM: C[z] = A[z] (MxK) * B[z>>bShift]^T (NxK) ----------------
__global__ __launch_bounds__(256) void gemm_bt(const unsigned short* __restrict__ A, long aStride, int lda,
                                               const unsigned short* __restrict__ B, long bStride, int bShift, int ldb,
                                               void* __restrict__ Cv, long cStride, int ldc,
                                               int K, float scale, int writeBf16) {
    __shared__ __align__(16) unsigned short As[64][40];
    __shared__ __align__(16) unsigned short Bs[64][40];
    const int tid = threadIdx.x;
    const int z = blockIdx.z;
    const unsigned short* Ab = A + (long)z * aStride + (long)(blockIdx.x * 64) * lda;
    const unsigned short* Bb = B + (long)(z >> bShift) * bStride + (long)(blockIdx.y * 64) * ldb;

    const int sr = tid >> 2;
    const int sc = (tid & 3) * 8;

    const int wv = tid >> 6;
    const int lane = tid & 63;
    const int m = lane & 15;
    const int qd = lane >> 4;

    floatx4 acc[4];
#pragma unroll
    for (int c = 0; c < 4; ++c) acc[c] = (floatx4){0.f, 0.f, 0.f, 0.f};

    for (int k0 = 0; k0 < K; k0 += 32) {
        __syncthreads();
        *(uint4*)&As[sr][sc] = *(const uint4*)(Ab + (long)sr * lda + k0 + sc);
        *(uint4*)&Bs[sr][sc] = *(const uint4*)(Bb + (long)sr * ldb + k0 + sc);
        __syncthreads();
        short8 a = *(const short8*)&As[wv * 16 + m][qd * 8];
#pragma unroll
        for (int c = 0; c < 4; ++c) {
            short8 b = *(const short8*)&Bs[c * 16 + m][qd * 8];
            acc[c] = __builtin_amdgcn_mfma_f32_16x16x32_bf16(a, b, acc[c], 0, 0, 0);
        }
    }

    const long crow0 = (long)blockIdx.x * 64 + wv * 16 + qd * 4;
    const int ccol0 = blockIdx.y * 64;
    if (writeBf16) {
        unsigned short* Cb = (unsigned short*)Cv + (long)z * cStride;
#pragma unroll
        for (int c = 0; c < 4; ++c)
#pragma unroll
            for (int r = 0; r < 4; ++r)
                Cb[(crow0 + r) * ldc + ccol0 + c * 16 + m] = f2bf(acc[c][r] * scale);
    } else {
        float* Cf = (float*)Cv + (long)z * cStride;
#pragma unroll
        for (int c = 0; c < 4; ++c)
#pragma unroll
            for (int r = 0; r < 4; ++r)
                Cf[(crow0 + r) * ldc + ccol0 + c * 16 + m] = acc[c][r] * scale;
    }
}

// ---------------- flash attention v2: barrier-free, per-wave independent ----------------
// grid(512), block 256. Block b: head h=b>>5, pair p=b&31.
// Wave wv handles one 16-row Q slice s in {2p, 2p+1, 126-2p, 127-2p} (balanced: ~67 iters/block).
// Q/K/V MFMA fragments loaded DIRECTLY from global (16B/lane, L2-resident).
// Only P takes a per-wave LDS round-trip (C-layout -> A-layout). No __syncthreads anywhere.
__global__ __launch_bounds__(256) void flash_attn(const unsigned short* __restrict__ qb,
                                                  const unsigned short* __restrict__ kb,
                                                  const unsigned short* __restrict__ vt,
                                                  unsigned short* __restrict__ ab) {
    __shared__ __align__(16) unsigned short Pls[4][16 * 72];
    const int tid = threadIdx.x;
    const int wv = tid >> 6;
    const int lane = tid & 63;
    const int m = lane & 15;
    const int qd = lane >> 4;
    const int h = blockIdx.x >> 5;
    const int p = blockIdx.x & 31;
    const int g = h >> 2;

    const int s = (wv == 0) ? 2 * p : (wv == 1) ? 2 * p + 1 : (wv == 2) ? 126 - 2 * p : 127 - 2 * p;
    const int q0 = s * 16;
    const int qrel_base = (s & 3) * 16 + qd * 4;   // q index within the last 64-key tile

    unsigned short* myP = Pls[wv];

    short8 aq[4];
#pragma unroll
    for (int kk = 0; kk < 4; ++kk)
        aq[kk] = *(const short8*)(qb + (long)(q0 + m) * Q_SIZE + h * HD + kk * 32 + qd * 8);

    floatx4 acc_o[8];
#pragma unroll
    for (int nb = 0; nb < 8; ++nb) acc_o[nb] = (floatx4){0.f, 0.f, 0.f, 0.f};
    float mrow[4] = {-1e30f, -1e30f, -1e30f, -1e30f};
    float lrow[4] = {0.f, 0.f, 0.f, 0.f};

    const float scale = 0.08838834764831845f;
    const int njt = (s >> 2) + 1;

    for (int jt = 0; jt < njt; ++jt) {
        const int j0 = jt * 64;
        const bool lastTile = (jt == njt - 1);

        floatx4 acc_s[4];
#pragma unroll
        for (int c = 0; c < 4; ++c) acc_s[c] = (floatx4){0.f, 0.f, 0.f, 0.f};
#pragma unroll
        for (int c = 0; c < 4; ++c) {
            const unsigned short* krow = kb + (long)(j0 + c * 16 + m) * KV_SIZE + g * HD + qd * 8;
#pragma unroll
            for (int kk = 0; kk < 4; ++kk) {
                short8 b = *(const short8*)(krow + kk * 32);
                acc_s[c] = __builtin_amdgcn_mfma_f32_16x16x32_bf16(aq[kk], b, acc_s[c], 0, 0, 0);
            }
        }

        float sv[4][4];
#pragma unroll
        for (int c = 0; c < 4; ++c)
#pragma unroll
            for (int r = 0; r < 4; ++r) sv[c][r] = acc_s[c][r] * scale;
        if (lastTile) {
#pragma unroll
            for (int c = 0; c < 4; ++c)
#pragma unroll
                for (int r = 0; r < 4; ++r)
                    if (c * 16 + m > qrel_base + r) sv[c][r] = -1e30f;
        }

        float alpha[4];
#pragma unroll
        for (int r = 0; r < 4; ++r) {
            float mx = fmaxf(fmaxf(sv[0][r], sv[1][r]), fmaxf(sv[2][r], sv[3][r]));
            mx = fmaxf(mx, __shfl_xor(mx, 1));
            mx = fmaxf(mx, __shfl_xor(mx, 2));
            mx = fmaxf(mx, __shfl_xor(mx, 4));
            mx = fmaxf(mx, __shfl_xor(mx, 8));
            float mnew = fmaxf(mrow[r], mx);
            alpha[r] = __expf(mrow[r] - mnew);
            mrow[r] = mnew;
        }
        float pv[4][4];
#pragma unroll
        for (int c = 0; c < 4; ++c)
#pragma unroll
            for (int r = 0; r < 4; ++r) pv[c][r] = __expf(sv[c][r] - mrow[r]);
#pragma unroll
        for (int r = 0; r < 4; ++r) {
            float sum = pv[0][r] + pv[1][r] + pv[2][r] + pv[3][r];
            sum += __shfl_xor(sum, 1);
            sum += __shfl_xor(sum, 2);
            sum += __shfl_xor(sum, 4);
            sum += __shfl_xor(sum, 8);
            lrow[r] = lrow[r] * alpha[r] + sum;
        }
#pragma unroll
        for (int nb = 0; nb < 8; ++nb)
#pragma unroll
            for (int r = 0; r < 4; ++r) acc_o[nb][r] *= alpha[r];

#pragma unroll
        for (int c = 0; c < 4; ++c)
#pragma unroll
            for (int r = 0; r < 4; ++r)
                myP[(qd * 4 + r) * 72 + c * 16 + m] = f2bf(pv[c][r]);

#pragma unroll
        for (int kk = 0; kk < 2; ++kk) {
            short8 pa = *(const short8*)&myP[m * 72 + kk * 32 + qd * 8];
#pragma unroll
            for (int nb = 0; nb < 8; ++nb) {
                short8 vbf = *(const short8*)(vt + ((long)g * HD + nb * 16 + m) * T + j0 + kk * 32 + qd * 8);
                acc_o[nb] = __builtin_amdgcn_mfma_f32_16x16x32_bf16(pa, vbf, acc_o[nb], 0, 0, 0);
            }
        }
    }

#pragma unroll
    for (int nb = 0; nb < 8; ++nb)
#pragma unroll
        for (int r = 0; r < 4; ++r)
            ab[(long)(q0 + qd * 4 + r) * Q_SIZE + h * HD + nb * 16 + m] =
                f2bf(acc_o[nb][r] / lrow[r]);
}

extern "C" void kernel_launch(void* const* d_in, const int* in_sizes, int n_in,
                              void* d_out, int out_size, void* d_ws, size_t ws_size,
                              hipStream_t stream) {
    const int* positions = (const int*)d_in[0];
    const float* hidden  = (const float*)d_in[1];
    const float* w_qkv   = (const float*)d_in[2];
    const float* w_o     = (const float*)d_in[3];
    float* out = (float*)d_out;

    char* p = (char*)d_ws;
    auto alloc = [&](size_t bytes) { char* r = p; p += (bytes + 255) & ~(size_t)255; return r; };
    float* cosT = (float*)alloc((size_t)T * 64 * 4);
    float* sinT = (float*)alloc((size_t)T * 64 * 4);
    float* qkv  = (float*)alloc((size_t)T * QKV_N * 4);
    unsigned short* hb  = (unsigned short*)alloc((size_t)T * HIDDEN * 2);
    unsigned short* wqt = (unsigned short*)alloc((size_t)QKV_N * HIDDEN * 2);
    unsigned short* wot = (unsigned short*)alloc((size_t)HIDDEN * HIDDEN * 2);
    unsigned short* qb  = (unsigned short*)alloc((size_t)T * Q_SIZE * 2);
    unsigned short* kb  = (unsigned short*)alloc((size_t)T * KV_SIZE * 2);
    unsigned short* vb  = (unsigned short*)alloc((size_t)T * KV_SIZE * 2);
    unsigned short* vt  = (unsigned short*)alloc((size_t)T * KV_SIZE * 2);
    unsigned short* ab  = (unsigned short*)alloc((size_t)T * Q_SIZE * 2);

    dim3 tb(32, 8);
    prep_cossin<<<T, 64, 0, stream>>>(positions, cosT, sinT);
    convert_f32_bf16<<<(T * HIDDEN) / 1024, 256, 0, stream>>>(hidden, hb, T * HIDDEN);
    transpose_f32_bf16<<<dim3(QKV_N / 32, HIDDEN / 32), tb, 0, stream>>>(w_qkv, wqt, HIDDEN, QKV_N);
    transpose_f32_bf16<<<dim3(HIDDEN / 32, HIDDEN / 32), tb, 0, stream>>>(w_o, wot, HIDDEN, HIDDEN);
    gemm_bt<<<dim3(T / 64, QKV_N / 64, 1), 256, 0, stream>>>(hb, 0, HIDDEN, wqt, 0, 0, HIDDEN,
                                                             qkv, 0, QKV_N, HIDDEN, 1.0f, 0);
    rope_split<<<T, 256, 0, stream>>>(qkv, cosT, sinT, qb, kb, vb);
    transpose_bf16<<<dim3(HD / 32, T / 32, NKV), tb, 0, stream>>>(vb, vt, T, HD);
    flash_attn<<<dim3(512), 256, 0, stream>>>(qb, kb, vt, ab);
    gemm_bt<<<dim3(T / 64, HIDDEN / 64, 1), 256, 0, stream>>>(ab, 0, Q_SIZE, wot, 0, 0, HIDDEN,
                                                              out, 0, HIDDEN, Q_SIZE, 1.0f, 0);
}

// Round 4
// 362.114 us; speedup vs baseline: 1.1401x; 1.1401x over previous
//
#include <hip/hip_runtime.h>
#include <math.h>

#define T 2048
#define HIDDEN 2048
#define NH 16
#define NKV 4
#define HD 128
#define QKV_N 3072   // (16 + 2*4) * 128
#define Q_SIZE 2048  // 16*128
#define KV_SIZE 512  // 4*128

typedef __attribute__((ext_vector_type(8))) short short8;
typedef __attribute__((ext_vector_type(4))) short short4v;
typedef __attribute__((ext_vector_type(4))) float floatx4;

__device__ __forceinline__ unsigned short f2bf(float f) {
    union { float f; unsigned int u; } v; v.f = f;
    unsigned int u = v.u;
    u += 0x7fffu + ((u >> 16) & 1u);   // round-to-nearest-even
    return (unsigned short)(u >> 16);
}
__device__ __forceinline__ float bf2f(unsigned short h) {
    union { unsigned int u; float f; } v; v.u = ((unsigned int)h) << 16;
    return v.f;
}

// async global->LDS, 16B per lane; LDS dest = wave-uniform base + lane*16 (HW adds it)
__device__ __forceinline__ void gload_lds16(const unsigned short* g, unsigned short* l) {
    __builtin_amdgcn_global_load_lds((const __attribute__((address_space(1))) unsigned int*)g,
                                     (__attribute__((address_space(3))) unsigned int*)l, 16, 0, 0);
}

// ---------------- cos/sin tables (mrope sectioning) ----------------
__global__ void prep_cossin(const int* __restrict__ positions,
                            float* __restrict__ cosT, float* __restrict__ sinT) {
    int t = blockIdx.x;
    int j = threadIdx.x;           // 0..63
    int row = (j >= 44) ? 0 : ((j & 1) ? 2 : 1);
    int pos = positions[row * T + t];
    double invf = pow(500000.0, -(double)j / 64.0);
    double ang = (double)pos * invf;
    cosT[t * 64 + j] = (float)cos(ang);
    sinT[t * 64 + j] = (float)sin(ang);
}

// ---------------- fp32 -> bf16 convert ----------------
__global__ __launch_bounds__(256) void convert_f32_bf16(const float* __restrict__ in,
                                                        unsigned short* __restrict__ out, int n) {
    int i = (blockIdx.x * 256 + threadIdx.x) * 4;
    if (i + 3 < n) {
        float4 v = *(const float4*)(in + i);
        out[i]     = f2bf(v.x);
        out[i + 1] = f2bf(v.y);
        out[i + 2] = f2bf(v.z);
        out[i + 3] = f2bf(v.w);
    }
}

// ---------------- transpose fp32 -> bf16 : out[c][r] = in[r][c] ----------------
__global__ __launch_bounds__(256) void transpose_f32_bf16(const float* __restrict__ in,
                                                          unsigned short* __restrict__ out,
                                                          int R, int C) {
    __shared__ float tile[32][33];
    int tx = threadIdx.x, ty = threadIdx.y;          // (32,8)
    int c0 = blockIdx.x * 32, r0 = blockIdx.y * 32;
#pragma unroll
    for (int i = 0; i < 4; ++i)
        tile[ty + i * 8][tx] = in[(long)(r0 + ty + i * 8) * C + c0 + tx];
    __syncthreads();
#pragma unroll
    for (int i = 0; i < 4; ++i)
        out[(long)(c0 + ty + i * 8) * R + r0 + tx] = f2bf(tile[tx][ty + i * 8]);
}

// ---------------- transpose bf16 (batched over z) ----------------
__global__ __launch_bounds__(256) void transpose_bf16(const unsigned short* __restrict__ in,
                                                      unsigned short* __restrict__ out,
                                                      int R, int C) {
    __shared__ unsigned short tile[32][33];
    long zo = (long)blockIdx.z * R * C;
    in += zo; out += zo;
    int tx = threadIdx.x, ty = threadIdx.y;
    int c0 = blockIdx.x * 32, r0 = blockIdx.y * 32;
#pragma unroll
    for (int i = 0; i < 4; ++i)
        tile[ty + i * 8][tx] = in[(long)(r0 + ty + i * 8) * C + c0 + tx];
    __syncthreads();
#pragma unroll
    for (int i = 0; i < 4; ++i)
        out[(long)(c0 + ty + i * 8) * R + r0 + tx] = tile[tx][ty + i * 8];
}

// ---------------- rope + split qkv -> q_bf (pre-scaled), k_bf, v_bf ----------------
__global__ __launch_bounds__(256) void rope_split(const float* __restrict__ qkv,
                                                  const float* __restrict__ cosT,
                                                  const float* __restrict__ sinT,
                                                  unsigned short* __restrict__ qb,
                                                  unsigned short* __restrict__ kb,
                                                  unsigned short* __restrict__ vb) {
    const float scale = 0.08838834764831845f;   // 1/sqrt(128), folded into Q
    int t = blockIdx.x, tid = threadIdx.x;
    const float* row = qkv + (long)t * QKV_N;
    const float* ct = cosT + t * 64;
    const float* st = sinT + t * 64;
    for (int i = tid; i < NH * 64; i += 256) {
        int h = i >> 6, j = i & 63;
        float c = ct[j], s = st[j];
        float x1 = row[h * HD + 2 * j], x2 = row[h * HD + 2 * j + 1];
        qb[(long)t * Q_SIZE + h * HD + 2 * j]     = f2bf((x1 * c - x2 * s) * scale);
        qb[(long)t * Q_SIZE + h * HD + 2 * j + 1] = f2bf((x2 * c + x1 * s) * scale);
    }
    {
        int i = tid;
        int g = i >> 6, j = i & 63;
        float c = ct[j], s = st[j];
        float x1 = row[Q_SIZE + g * HD + 2 * j], x2 = row[Q_SIZE + g * HD + 2 * j + 1];
        kb[(long)t * KV_SIZE + g * HD + 2 * j]     = f2bf(x1 * c - x2 * s);
        kb[(long)t * KV_SIZE + g * HD + 2 * j + 1] = f2bf(x2 * c + x1 * s);
    }
    for (int i = tid; i < KV_SIZE; i += 256) {
        int g = i >> 7, d = i & 127;
        vb[((long)g * T + t) * HD + d] = f2bf(row[Q_SIZE + KV_SIZE + g * HD + d]);
    }
}

// ---------------- GEMM m97-style: C(fp32, MxN) = A(bf16 MxK) * B^T(bf16 NxK) ----------------
// 128x128 tile, 4 waves (2x2 of 64x64), BK=32, global_load_lds width 16, unpadded LDS tiles.
__global__ __launch_bounds__(256) void gemm_bt128(const unsigned short* __restrict__ A,
                                                  const unsigned short* __restrict__ B,
                                                  float* __restrict__ C,
                                                  int K, int ldc) {
    __shared__ __align__(16) unsigned short As[128 * 32];
    __shared__ __align__(16) unsigned short Bs[128 * 32];
    const int tid = threadIdx.x;
    const int wv = tid >> 6;
    const int wr = wv >> 1, wc = wv & 1;
    const int lane = tid & 63;
    const int m = lane & 15, qd = lane >> 4;
    const unsigned short* Ab = A + (long)(blockIdx.x * 128) * K;
    const unsigned short* Bb = B + (long)(blockIdx.y * 128) * K;

    const int srow = lane >> 2;          // 0..15 within wave's 16-row chunk
    const int scol = (lane & 3) * 8;     // shorts

    floatx4 acc[4][4];
#pragma unroll
    for (int i = 0; i < 4; ++i)
#pragma unroll
        for (int j = 0; j < 4; ++j) acc[i][j] = (floatx4){0.f, 0.f, 0.f, 0.f};

    for (int k0 = 0; k0 < K; k0 += 32) {
        __syncthreads();
        gload_lds16(Ab + (long)(wv * 16 + srow) * K + k0 + scol,        &As[wv * 512]);
        gload_lds16(Ab + (long)(64 + wv * 16 + srow) * K + k0 + scol,   &As[2048 + wv * 512]);
        gload_lds16(Bb + (long)(wv * 16 + srow) * K + k0 + scol,        &Bs[wv * 512]);
        gload_lds16(Bb + (long)(64 + wv * 16 + srow) * K + k0 + scol,   &Bs[2048 + wv * 512]);
        __syncthreads();
        short8 a[4], b[4];
#pragma unroll
        for (int i = 0; i < 4; ++i) a[i] = *(const short8*)&As[(wr * 64 + i * 16 + m) * 32 + qd * 8];
#pragma unroll
        for (int j = 0; j < 4; ++j) b[j] = *(const short8*)&Bs[(wc * 64 + j * 16 + m) * 32 + qd * 8];
#pragma unroll
        for (int i = 0; i < 4; ++i)
#pragma unroll
            for (int j = 0; j < 4; ++j)
                acc[i][j] = __builtin_amdgcn_mfma_f32_16x16x32_bf16(a[i], b[j], acc[i][j], 0, 0, 0);
    }

#pragma unroll
    for (int i = 0; i < 4; ++i)
#pragma unroll
        for (int j = 0; j < 4; ++j)
#pragma unroll
            for (int r = 0; r < 4; ++r)
                C[(long)(blockIdx.x * 128 + wr * 64 + i * 16 + qd * 4 + r) * ldc +
                  blockIdx.y * 128 + wc * 64 + j * 16 + m] = acc[i][j][r];
}

// ---------------- flash attention v3: LDS-staged, reg-prefetch pipeline, K-split x2, S^T softmax ----
// grid(1024): bx = h*64 + qt*2 + half. Block: 64 Q-rows (wave wv -> rows wv*16+m), keys split in halves.
// Partials (unnormalized O^T, m, l) -> Opart/MLpart fp32; attn_combine merges.
__global__ __launch_bounds__(256) void flash_attn(const unsigned short* __restrict__ qb,
                                                  const unsigned short* __restrict__ kb,
                                                  const unsigned short* __restrict__ vt,
                                                  float* __restrict__ Opart,
                                                  float* __restrict__ MLpart) {
    __shared__ __align__(16) unsigned short Ks[64 * 136];
    __shared__ __align__(16) unsigned short Vts[128 * 72];
    __shared__ __align__(16) unsigned short Pls[4][16 * 72];

    const int tid = threadIdx.x;
    const int wv = tid >> 6;
    const int lane = tid & 63;
    const int m = lane & 15;
    const int qd = lane >> 4;

    const int bx = blockIdx.x;
    const int h = bx >> 6;
    const int qt = (bx >> 1) & 31;
    const int half = bx & 1;
    const int g = h >> 2;

    const int n = qt + 1;
    const int n0 = (n + 1) >> 1;
    const int jt0 = half ? n0 : 0;
    const int jt1 = half ? n : n0;

    const int q0 = qt * 64;
    const int krow = tid >> 2, kcolb = (tid & 3) * 8;
    const int vrow = tid >> 1, vcolb = (tid & 1) * 8;

    unsigned short* myP = Pls[wv];

    // Q fragments (B-operand rows = q = wv*16+m); Q pre-scaled by 1/sqrt(d)
    short8 aq[4];
#pragma unroll
    for (int kk = 0; kk < 4; ++kk)
        aq[kk] = *(const short8*)(qb + (long)(q0 + wv * 16 + m) * Q_SIZE + h * HD + kk * 32 + qd * 8);

    floatx4 acc_o[8];
#pragma unroll
    for (int nb = 0; nb < 8; ++nb) acc_o[nb] = (floatx4){0.f, 0.f, 0.f, 0.f};
    float mrow = -1e30f, lrow = 0.f;

    if (jt0 < jt1) {
        uint4 kreg[4], vreg[4];
        {
            const unsigned short* kp = kb + (long)(jt0 * 64 + krow) * KV_SIZE + g * HD + kcolb;
#pragma unroll
            for (int c4 = 0; c4 < 4; ++c4) kreg[c4] = *(const uint4*)(kp + c4 * 32);
            const unsigned short* vp = vt + ((long)g * HD + vrow) * T + jt0 * 64 + vcolb;
#pragma unroll
            for (int c4 = 0; c4 < 4; ++c4) vreg[c4] = *(const uint4*)(vp + c4 * 16);
        }
        for (int jt = jt0; jt < jt1; ++jt) {
            if (jt > jt0) __syncthreads();          // LDS readers of prev tile done
#pragma unroll
            for (int c4 = 0; c4 < 4; ++c4) *(uint4*)&Ks[krow * 136 + kcolb + c4 * 32] = kreg[c4];
#pragma unroll
            for (int c4 = 0; c4 < 4; ++c4) *(uint4*)&Vts[vrow * 72 + vcolb + c4 * 16] = vreg[c4];
            __syncthreads();
            if (jt + 1 < jt1) {                     // prefetch next tile (overlaps compute)
                const unsigned short* kp = kb + (long)((jt + 1) * 64 + krow) * KV_SIZE + g * HD + kcolb;
#pragma unroll
                for (int c4 = 0; c4 < 4; ++c4) kreg[c4] = *(const uint4*)(kp + c4 * 32);
                const unsigned short* vp = vt + ((long)g * HD + vrow) * T + (jt + 1) * 64 + vcolb;
#pragma unroll
                for (int c4 = 0; c4 < 4; ++c4) vreg[c4] = *(const uint4*)(vp + c4 * 16);
            }

            // S^T = K Q^T : D rows = keys (c*16+qd*4+r), cols = q (m)
            floatx4 acc_s[4];
#pragma unroll
            for (int c = 0; c < 4; ++c) acc_s[c] = (floatx4){0.f, 0.f, 0.f, 0.f};
#pragma unroll
            for (int kk = 0; kk < 4; ++kk) {
#pragma unroll
                for (int c = 0; c < 4; ++c) {
                    short8 ak = *(const short8*)&Ks[(c * 16 + m) * 136 + kk * 32 + qd * 8];
                    acc_s[c] = __builtin_amdgcn_mfma_f32_16x16x32_bf16(ak, aq[kk], acc_s[c], 0, 0, 0);
                }
            }

            float sv[4][4];
#pragma unroll
            for (int c = 0; c < 4; ++c)
#pragma unroll
                for (int r = 0; r < 4; ++r) sv[c][r] = acc_s[c][r];
            if (jt == qt) {   // diagonal tile: mask key > q
#pragma unroll
                for (int c = 0; c < 4; ++c)
#pragma unroll
                    for (int r = 0; r < 4; ++r)
                        if (c * 16 + qd * 4 + r > wv * 16 + m) sv[c][r] = -1e30f;
            }

            // max over 64 keys: register tree (16) + 2 shuffles across qd lanes
            float mx = sv[0][0];
#pragma unroll
            for (int c = 0; c < 4; ++c)
#pragma unroll
                for (int r = 0; r < 4; ++r) mx = fmaxf(mx, sv[c][r]);
            mx = fmaxf(mx, __shfl_xor(mx, 16));
            mx = fmaxf(mx, __shfl_xor(mx, 32));
            float mnew = fmaxf(mrow, mx);
            float alpha = __expf(mrow - mnew);
            mrow = mnew;

            float pv[4][4];
            float lsum = 0.f;
#pragma unroll
            for (int c = 0; c < 4; ++c)
#pragma unroll
                for (int r = 0; r < 4; ++r) {
                    pv[c][r] = __expf(sv[c][r] - mnew);
                    lsum += pv[c][r];
                }
            lsum += __shfl_xor(lsum, 16);
            lsum += __shfl_xor(lsum, 32);
            lrow = lrow * alpha + lsum;
#pragma unroll
            for (int nb = 0; nb < 8; ++nb)
#pragma unroll
                for (int r = 0; r < 4; ++r) acc_o[nb][r] *= alpha;

            // P: pack 4 bf16 per acc -> per-wave LDS (B-layout rows q=m), then PV
#pragma unroll
            for (int c = 0; c < 4; ++c) {
                short4v pk = {(short)f2bf(pv[c][0]), (short)f2bf(pv[c][1]),
                              (short)f2bf(pv[c][2]), (short)f2bf(pv[c][3])};
                *(short4v*)&myP[m * 72 + c * 16 + qd * 4] = pk;
            }
#pragma unroll
            for (int kk = 0; kk < 2; ++kk) {
                short8 pa = *(const short8*)&myP[m * 72 + kk * 32 + qd * 8];
#pragma unroll
                for (int nb = 0; nb < 8; ++nb) {
                    short8 av = *(const short8*)&Vts[(nb * 16 + m) * 72 + kk * 32 + qd * 8];
                    acc_o[nb] = __builtin_amdgcn_mfma_f32_16x16x32_bf16(av, pa, acc_o[nb], 0, 0, 0);
                }
            }
        }
    }

    // store partials: O^T layout -> Opart[(bx*64 + q_local)*128 + d], fp32 unnormalized
    const long rbase = (long)bx * 64 + wv * 16 + m;
#pragma unroll
    for (int nb = 0; nb < 8; ++nb)
        *(floatx4*)&Opart[rbase * 128 + nb * 16 + qd * 4] = acc_o[nb];
    if (qd == 0) {
        MLpart[rbase * 2]     = mrow;
        MLpart[rbase * 2 + 1] = lrow;
    }
}

// ---------------- combine K-split partials -> ab bf16 [t][h*128+d] ----------------
__global__ __launch_bounds__(256) void attn_combine(const float* __restrict__ Opart,
                                                    const float* __restrict__ MLpart,
                                                    unsigned short* __restrict__ ab) {
    const int tid = threadIdx.x;
    const int q = blockIdx.x * 16 + (tid >> 4);
    const int h = blockIdx.y;
    const int d0 = (tid & 15) * 8;
    const int qt = q >> 6, lr = q & 63;
    const long r0 = ((long)(h * 64 + qt * 2)) * 64 + lr;
    const long r1 = r0 + 64;
    float m0 = MLpart[r0 * 2], l0 = MLpart[r0 * 2 + 1];
    float m1 = MLpart[r1 * 2], l1 = MLpart[r1 * 2 + 1];
    float M = fmaxf(m0, m1);
    float a0 = __expf(m0 - M), a1 = __expf(m1 - M);
    float inv = 1.f / (l0 * a0 + l1 * a1);
    const float* O0 = Opart + r0 * 128 + d0;
    const float* O1 = Opart + r1 * 128 + d0;
    unsigned short outv[8];
#pragma unroll
    for (int j = 0; j < 8; j += 4) {
        float4 x0 = *(const float4*)(O0 + j);
        float4 x1 = *(const float4*)(O1 + j);
        outv[j]     = f2bf((x0.x * a0 + x1.x * a1) * inv);
        outv[j + 1] = f2bf((x0.y * a0 + x1.y * a1) * inv);
        outv[j + 2] = f2bf((x0.z * a0 + x1.z * a1) * inv);
        outv[j + 3] = f2bf((x0.w * a0 + x1.w * a1) * inv);
    }
    *(short8*)&ab[(long)q * Q_SIZE + h * HD + d0] = *(short8*)outv;
}

extern "C" void kernel_launch(void* const* d_in, const int* in_sizes, int n_in,
                              void* d_out, int out_size, void* d_ws, size_t ws_size,
                              hipStream_t stream) {
    const int* positions = (const int*)d_in[0];
    const float* hidden  = (const float*)d_in[1];
    const float* w_qkv   = (const float*)d_in[2];
    const float* w_o     = (const float*)d_in[3];
    float* out = (float*)d_out;

    char* p = (char*)d_ws;
    auto alloc = [&](size_t bytes) { char* r = p; p += (bytes + 255) & ~(size_t)255; return r; };
    float* cosT = (float*)alloc((size_t)T * 64 * 4);
    float* sinT = (float*)alloc((size_t)T * 64 * 4);
    float* qkv  = (float*)alloc((size_t)T * QKV_N * 4);
    unsigned short* hb  = (unsigned short*)alloc((size_t)T * HIDDEN * 2);
    unsigned short* wqt = (unsigned short*)alloc((size_t)QKV_N * HIDDEN * 2);
    unsigned short* wot = (unsigned short*)alloc((size_t)HIDDEN * HIDDEN * 2);
    unsigned short* qb  = (unsigned short*)alloc((size_t)T * Q_SIZE * 2);
    unsigned short* kb  = (unsigned short*)alloc((size_t)T * KV_SIZE * 2);
    unsigned short* vb  = (unsigned short*)alloc((size_t)T * KV_SIZE * 2);
    unsigned short* vt  = (unsigned short*)alloc((size_t)T * KV_SIZE * 2);
    unsigned short* ab  = (unsigned short*)alloc((size_t)T * Q_SIZE * 2);
    float* Opart  = (float*)alloc((size_t)1024 * 64 * 128 * 4);   // 33.5 MB
    float* MLpart = (float*)alloc((size_t)1024 * 64 * 2 * 4);

    dim3 tb(32, 8);
    prep_cossin<<<T, 64, 0, stream>>>(positions, cosT, sinT);
    convert_f32_bf16<<<(T * HIDDEN) / 1024, 256, 0, stream>>>(hidden, hb, T * HIDDEN);
    transpose_f32_bf16<<<dim3(QKV_N / 32, HIDDEN / 32), tb, 0, stream>>>(w_qkv, wqt, HIDDEN, QKV_N);
    transpose_f32_bf16<<<dim3(HIDDEN / 32, HIDDEN / 32), tb, 0, stream>>>(w_o, wot, HIDDEN, HIDDEN);
    // qkv = hidden @ w_qkv (fp32 out)
    gemm_bt128<<<dim3(T / 128, QKV_N / 128), 256, 0, stream>>>(hb, wqt, qkv, HIDDEN, QKV_N);
    rope_split<<<T, 256, 0, stream>>>(qkv, cosT, sinT, qb, kb, vb);
    transpose_bf16<<<dim3(HD / 32, T / 32, NKV), tb, 0, stream>>>(vb, vt, T, HD);
    // fused causal attention, K-split x2 -> partials -> combine -> ab bf16
    flash_attn<<<dim3(1024), 256, 0, stream>>>(qb, kb, vt, Opart, MLpart);
    attn_combine<<<dim3(T / 16, NH), 256, 0, stream>>>(Opart, MLpart, ab);
    // out = attn @ w_o (fp32 out)
    gemm_bt128<<<dim3(T / 128, HIDDEN / 128), 256, 0, stream>>>(ab, wot, out, Q_SIZE, HIDDEN);
}